// Round 15
// baseline (42.578 us; speedup 1.0000x reference)
//
#include <hip/hip_runtime.h>
#include <math.h>

#define W_ 128
#define H_ 96
#define C_ 128
#define HW_ (H_ * W_)          // 12288
#define K_ 81
#define FLOW_ELEMS (2 * 2 * H_ * W_)   // 49152
#define TCOLS 80               // staged xp cols per block (wave tiles need <= 79)
#define TSTR 66                // u32 stride per col: even (8B-aligned b64), 2-way banks

typedef __fp16 f16x8 __attribute__((ext_vector_type(8)));
typedef float  f32x4 __attribute__((ext_vector_type(4)));

__device__ __forceinline__ unsigned pack_pair(float a, float b) {
    return __builtin_bit_cast(unsigned, __builtin_amdgcn_cvt_pkrtz(a, b));
}

// Single fused kernel: block = 256 thr (4 waves) per (b, y0, xh) = 64 pixels.
// Per dy: stage f1 halo row (80 cols x 128 ch, packed f16 pairs) into LDS,
// then each wave does 8 mfma_f32_16x16x32_f16 (16-px A-tile x 32 sample cols),
// band dx in [0,8] -> corr_lds. Then in-block softmax + flow + prob writeout.
// A-frag / band-extract / softmax code identical to the R14 PASSING kernel.
// Grid = 384 blocks (8 XCD chunks x 48). No workspace, no other kernels.
__global__ __launch_bounds__(256) void fused_kernel(const float* __restrict__ f0,
                                                    const float* __restrict__ f1,
                                                    float* __restrict__ out) {
    __shared__ unsigned tile[TCOLS * TSTR];   // [col][cp]: col=xp_local, cp=ch pair
    __shared__ float corr_lds[64][85];        // stride 85
    __shared__ float mbuf[64], ibuf[64];

    const int t = threadIdx.x;
    const int wid = t >> 6, l = t & 63;
    const int L = (blockIdx.x & 7) * 48 + (blockIdx.x >> 3);   // 384 = 8*48
    const int xh = L & 1;
    const int y0 = (L >> 1) % H_;
    const int b  = L / (2 * H_);
    const int px0 = xh * 64 + wid * 16;       // wave's absolute pixel base

    for (int i = t; i < 64 * 85; i += 256) (&corr_lds[0][0])[i] = 0.f;

    // ---- A-frags straight from f32 f0 (R14-verified): row=l&15, k=(l>>4)*8+j ----
    f16x8 a[4];
    {
        const float* f0p = f0 + (size_t)b * C_ * HW_ + (size_t)y0 * W_ + px0 + (l & 15);
#pragma unroll
        for (int kk = 0; kk < 4; ++kk) {
            f16x8 av;
#pragma unroll
            for (int j = 0; j < 8; ++j)
                av[j] = (__fp16)f0p[(size_t)(kk * 32 + (l >> 4) * 8 + j) * HW_];
            a[kk] = av;
        }
    }
    __syncthreads();   // corr_lds zero visible

    for (int dy = 0; dy < 9; ++dy) {
        const int r = y0 + dy - 4;            // block-uniform; uniform skip is safe
        if (r < 0 || r >= H_) continue;

        // ---- stage f1 row r: 40 col-pairs x 64 cp = 2560 slots, 10/thread ----
        // col c <-> sample x = xh*64 + c - 4 ; zeros outside [0,127] (exact padding)
        const float* f1b = f1 + (size_t)b * C_ * HW_ + (size_t)r * W_;
#pragma unroll
        for (int i = 0; i < 10; ++i) {
            const int s = i * 256 + t;
            const int cp = s / 40;
            const int cpair = s - cp * 40;
            const int x0 = xh * 64 + 2 * cpair - 4;   // even; pair fully in/out
            unsigned w0 = 0u, w1 = 0u;
            if (x0 >= 0 && x0 <= 126) {
                const float2 va = *(const float2*)(f1b + (size_t)(2 * cp) * HW_ + x0);
                const float2 vb = *(const float2*)(f1b + (size_t)(2 * cp + 1) * HW_ + x0);
                w0 = pack_pair(va.x, vb.x);
                w1 = pack_pair(va.y, vb.y);
            }
            tile[(2 * cpair) * TSTR + cp] = w0;
            tile[(2 * cpair + 1) * TSTR + cp] = w1;
        }
        __syncthreads();                      // staged tile visible to all waves

        // ---- MFMA: D = A(16x128) x B(128x32) as two 16-col tiles ----
        f32x4 accA = {0.f, 0.f, 0.f, 0.f}, accB = {0.f, 0.f, 0.f, 0.f};
#pragma unroll
        for (int kk = 0; kk < 4; ++kk) {
            const int off = kk * 16 + (l >> 4) * 4;   // u32 offset: k = kk*32+(l>>4)*8+j
            {
                const int col = wid * 16 + (l & 15);
                const uint2 lo = *(const uint2*)&tile[col * TSTR + off];
                const uint2 hi = *(const uint2*)&tile[col * TSTR + off + 2];
                const uint4 u = {lo.x, lo.y, hi.x, hi.y};
                accA = __builtin_amdgcn_mfma_f32_16x16x32_f16(
                    a[kk], __builtin_bit_cast(f16x8, u), accA, 0, 0, 0);
            }
            {
                const int col = wid * 16 + 16 + (l & 15);   // max 79 < TCOLS
                const uint2 lo = *(const uint2*)&tile[col * TSTR + off];
                const uint2 hi = *(const uint2*)&tile[col * TSTR + off + 2];
                const uint4 u = {lo.x, lo.y, hi.x, hi.y};
                accB = __builtin_amdgcn_mfma_f32_16x16x32_f16(
                    a[kk], __builtin_bit_cast(f16x8, u), accB, 0, 0, 0);
            }
        }

        // ---- band extraction (R14-verified): C col=l&15, row=(l>>4)*4+rg ----
#pragma unroll
        for (int h = 0; h < 2; ++h) {
            const f32x4 acc = h ? accB : accA;
#pragma unroll
            for (int rg = 0; rg < 4; ++rg) {
                const int i2 = (l >> 4) * 4 + rg;
                const int j2 = h * 16 + (l & 15);
                const int dxw = j2 - i2;
                if (dxw >= 0 && dxw <= 8)
                    corr_lds[wid * 16 + i2][dy * 9 + dxw] = acc[rg];
            }
        }
        __syncthreads();                      // tile reads done before next stage
    }
    __syncthreads();                          // corr_lds complete

    const float scale = 0.08838834764831845f;     // 1/sqrt(128)

    // ---- pass 1: thread-per-px softmax + flow (R14-verified) ----
    if (t < 64) {
        float m = -1e30f;
#pragma unroll 9
        for (int k = 0; k < K_; ++k) m = fmaxf(m, corr_lds[t][k] * scale);
        float s = 0.f, fx = 0.f, fy = 0.f;
#pragma unroll 9
        for (int k = 0; k < K_; ++k) {
            const float e = __expf(corr_lds[t][k] * scale - m);
            s += e;
            fx += e * (float)(k % 9 - 4);
            fy += e * (float)(k / 9 - 4);
        }
        const float inv = 1.f / s;
        mbuf[t] = m;
        ibuf[t] = inv;
        const int x = xh * 64 + t;
        out[((size_t)(b * 2 + 0) * H_ + y0) * W_ + x] = fx * inv;
        out[((size_t)(b * 2 + 1) * H_ + y0) * W_ + x] = fy * inv;
    }
    __syncthreads();

    // ---- pass 2: coalesced match_prob writeout (R14-verified) ----
    float* mp = out + FLOW_ELEMS + ((size_t)b * HW_ + (size_t)y0 * W_ + xh * 64) * K_;
    for (int f = t; f < 64 * K_; f += 256) {
        const int px = f / K_;
        const int k = f - px * K_;
        mp[f] = __expf(corr_lds[px][k] * scale - mbuf[px]) * ibuf[px];
    }
}

extern "C" void kernel_launch(void* const* d_in, const int* in_sizes, int n_in,
                              void* d_out, int out_size, void* d_ws, size_t ws_size,
                              hipStream_t stream) {
    (void)in_sizes; (void)n_in; (void)out_size; (void)d_ws; (void)ws_size;
    const float* f0 = (const float*)d_in[0];
    const float* f1 = (const float*)d_in[1];
    float* out = (float*)d_out;

    fused_kernel<<<384, 256, 0, stream>>>(f0, f1, out);
}

// Round 16
// 29.860 us; speedup vs baseline: 1.4259x; 1.4259x over previous
//
#include <hip/hip_runtime.h>
#include <math.h>

#define W_ 128
#define H_ 96
#define C_ 128
#define HW_ (H_ * W_)          // 12288
#define K_ 81
#define FLOW_ELEMS (2 * 2 * H_ * W_)   // 49152
#define TCOLS 80               // staged xp cols per block (wave tiles need <= 79)
#define TSTR 66                // u32 stride per col: even (8B-aligned b64), 2-way banks

typedef __fp16 f16x8 __attribute__((ext_vector_type(8)));
typedef float  f32x4 __attribute__((ext_vector_type(4)));

__device__ __forceinline__ unsigned pack_pair(float a, float b) {
    return __builtin_bit_cast(unsigned, __builtin_amdgcn_cvt_pkrtz(a, b));
}

// Single fused kernel (R15-verified structure), round 16: software-pipelined
// dy loop. Per dy: WRITE staged regs -> barrier -> issue NEXT dy's global
// loads (in flight across MFMA) -> MFMA + band extract -> barrier.
// Named A/B register sets, static indexing throughout (rule #20).
// Block = 256 thr (4 waves) per (b, y0, xh) = 64 px. Grid = 384 (8 XCD x 48).
__global__ __launch_bounds__(256) void fused_kernel(const float* __restrict__ f0,
                                                    const float* __restrict__ f1,
                                                    float* __restrict__ out) {
    __shared__ unsigned tile[TCOLS * TSTR];   // [col][cp]: col=xp_local, cp=ch pair
    __shared__ float corr_lds[64][85];        // stride 85
    __shared__ float mbuf[64], ibuf[64];

    const int t = threadIdx.x;
    const int wid = t >> 6, l = t & 63;
    const int L = (blockIdx.x & 7) * 48 + (blockIdx.x >> 3);   // 384 = 8*48
    const int xh = L & 1;
    const int y0 = (L >> 1) % H_;
    const int b  = L / (2 * H_);
    const int px0 = xh * 64 + wid * 16;       // wave's absolute pixel base

    for (int i = t; i < 64 * 85; i += 256) (&corr_lds[0][0])[i] = 0.f;

    // ---- per-slot staging constants (R15-verified mapping), kept in regs ----
    // slot s = i*256+t: cp = s/40 (ch pair), cpair = s%40 (col pair);
    // col c <-> sample x = xh*64 + c - 4; zeros outside [0,127].
    int g_off[10], lds_a[10];
    bool g_ok[10];
#pragma unroll
    for (int i = 0; i < 10; ++i) {
        const int s = i * 256 + t;
        const int cp = s / 40;
        const int cpair = s - cp * 40;
        const int x0 = xh * 64 + 2 * cpair - 4;
        g_ok[i] = (x0 >= 0) && (x0 <= 126);
        g_off[i] = 2 * cp * HW_ + (g_ok[i] ? x0 : 0);
        lds_a[i] = (2 * cpair) * TSTR + cp;
    }
    const float* f1base = f1 + (size_t)b * C_ * HW_;

    // ---- A-frags straight from f32 f0 (R14-verified): row=l&15, k=(l>>4)*8+j ----
    f16x8 a[4];
    {
        const float* f0p = f0 + (size_t)b * C_ * HW_ + (size_t)y0 * W_ + px0 + (l & 15);
#pragma unroll
        for (int kk = 0; kk < 4; ++kk) {
            f16x8 av;
#pragma unroll
            for (int j = 0; j < 8; ++j)
                av[j] = (__fp16)f0p[(size_t)(kk * 32 + (l >> 4) * 8 + j) * HW_];
            a[kk] = av;
        }
    }

    // ---- pipeline helpers (named reg sets; pure loads, pack deferred) ----
    auto LOADDY = [&](int dy, float2 (&va)[10], float2 (&vb)[10], bool& ok) {
        const int r = y0 + dy - 4;
        ok = (r >= 0) && (r < H_);
        const float* f1b = f1base + (size_t)(ok ? r : 0) * W_;
#pragma unroll
        for (int i = 0; i < 10; ++i) {
            float2 x = {0.f, 0.f}, y = {0.f, 0.f};
            if (ok && g_ok[i]) {
                x = *(const float2*)(f1b + g_off[i]);
                y = *(const float2*)(f1b + g_off[i] + HW_);
            }
            va[i] = x; vb[i] = y;
        }
    };
    auto WRITEDY = [&](const float2 (&va)[10], const float2 (&vb)[10]) {
#pragma unroll
        for (int i = 0; i < 10; ++i) {
            tile[lds_a[i]]        = pack_pair(va[i].x, vb[i].x);
            tile[lds_a[i] + TSTR] = pack_pair(va[i].y, vb[i].y);
        }
    };
    auto COMPUTE = [&](int dy) {
        f32x4 accA = {0.f, 0.f, 0.f, 0.f}, accB = {0.f, 0.f, 0.f, 0.f};
#pragma unroll
        for (int kk = 0; kk < 4; ++kk) {
            const int off = kk * 16 + (l >> 4) * 4;
            {
                const int col = wid * 16 + (l & 15);
                const uint2 lo = *(const uint2*)&tile[col * TSTR + off];
                const uint2 hi = *(const uint2*)&tile[col * TSTR + off + 2];
                const uint4 u = {lo.x, lo.y, hi.x, hi.y};
                accA = __builtin_amdgcn_mfma_f32_16x16x32_f16(
                    a[kk], __builtin_bit_cast(f16x8, u), accA, 0, 0, 0);
            }
            {
                const int col = wid * 16 + 16 + (l & 15);
                const uint2 lo = *(const uint2*)&tile[col * TSTR + off];
                const uint2 hi = *(const uint2*)&tile[col * TSTR + off + 2];
                const uint4 u = {lo.x, lo.y, hi.x, hi.y};
                accB = __builtin_amdgcn_mfma_f32_16x16x32_f16(
                    a[kk], __builtin_bit_cast(f16x8, u), accB, 0, 0, 0);
            }
        }
#pragma unroll
        for (int h = 0; h < 2; ++h) {
            const f32x4 acc = h ? accB : accA;
#pragma unroll
            for (int rg = 0; rg < 4; ++rg) {
                const int i2 = (l >> 4) * 4 + rg;
                const int j2 = h * 16 + (l & 15);
                const int dxw = j2 - i2;
                if (dxw >= 0 && dxw <= 8)
                    corr_lds[wid * 16 + i2][dy * 9 + dxw] = acc[rg];
            }
        }
    };

    float2 vaA[10], vbA[10], vaB[10], vbB[10];
    bool okA, okB;

    LOADDY(0, vaA, vbA, okA);
    __syncthreads();                      // corr_lds zero visible

#pragma unroll
    for (int d2 = 0; d2 < 5; ++d2) {
        {   // even dy = 2*d2 (uses A)
            const int dy = 2 * d2;
            if (okA) WRITEDY(vaA, vbA);   // vmcnt wait lands here, not earlier
            __syncthreads();              // staged tile visible
            if (dy + 1 < 9) LOADDY(dy + 1, vaB, vbB, okB);   // in flight over MFMA
            if (okA) COMPUTE(dy);
            __syncthreads();              // tile reads done before next write
        }
        if (2 * d2 + 1 < 9) {             // odd dy (uses B)
            const int dy = 2 * d2 + 1;
            if (okB) WRITEDY(vaB, vbB);
            __syncthreads();
            if (dy + 1 < 9) LOADDY(dy + 1, vaA, vbA, okA);
            if (okB) COMPUTE(dy);
            __syncthreads();
        }
    }

    const float scale = 0.08838834764831845f;     // 1/sqrt(128)

    // ---- pass 1: thread-per-px softmax + flow (R14-verified) ----
    if (t < 64) {
        float m = -1e30f;
#pragma unroll 9
        for (int k = 0; k < K_; ++k) m = fmaxf(m, corr_lds[t][k] * scale);
        float s = 0.f, fx = 0.f, fy = 0.f;
#pragma unroll 9
        for (int k = 0; k < K_; ++k) {
            const float e = __expf(corr_lds[t][k] * scale - m);
            s += e;
            fx += e * (float)(k % 9 - 4);
            fy += e * (float)(k / 9 - 4);
        }
        const float inv = 1.f / s;
        mbuf[t] = m;
        ibuf[t] = inv;
        const int x = xh * 64 + t;
        out[((size_t)(b * 2 + 0) * H_ + y0) * W_ + x] = fx * inv;
        out[((size_t)(b * 2 + 1) * H_ + y0) * W_ + x] = fy * inv;
    }
    __syncthreads();

    // ---- pass 2: coalesced match_prob writeout (R14-verified) ----
    float* mp = out + FLOW_ELEMS + ((size_t)b * HW_ + (size_t)y0 * W_ + xh * 64) * K_;
    for (int f = t; f < 64 * K_; f += 256) {
        const int px = f / K_;
        const int k = f - px * K_;
        mp[f] = __expf(corr_lds[px][k] * scale - mbuf[px]) * ibuf[px];
    }
}

extern "C" void kernel_launch(void* const* d_in, const int* in_sizes, int n_in,
                              void* d_out, int out_size, void* d_ws, size_t ws_size,
                              hipStream_t stream) {
    (void)in_sizes; (void)n_in; (void)out_size; (void)d_ws; (void)ws_size;
    const float* f0 = (const float*)d_in[0];
    const float* f1 = (const float*)d_in[1];
    float* out = (float*)d_out;

    fused_kernel<<<384, 256, 0, stream>>>(f0, f1, out);
}